// Round 12
// baseline (98.320 us; speedup 1.0000x reference)
//
#include <hip/hip_runtime.h>
#include <stdint.h>

// HamiltonianFlow: x [256, 8, 32, 2] (q,p); H = 0.5*sum(p^2) + MLP(q).
// dq/dt = p, dp/dt = -W u(z), z = W^T q + b1, u = (1-tanh^2(z)).*W2.
// z-space iteration with M = W^T W (R15-R23 verified).
//
// R34 = R33 combo-linearity DOUBLED: 16 steps/exchange, 7 barriers
// (6 x 16-step + 4-step tail). R33 (40.5us, bit-identical absmax)
// validated pre-summed combos (row 2j = uA_j = ua+ub+uc, row 2j+1 =
// uB_j = ua+2ub+2uc+ud; 2 rows/step). Measured tax ~1.26k cyc/exchange
// (R30 25exch/42us vs R33 13exch/36us regression) -> halve exchanges
// again with TWO combo tiles per barrier (tile0 = steps 0-7, tile1 =
// steps 8-15), two 8-MFMA blocks (4 indep chains). Lane owns steps
// j in {2q, 2q+1, 2q+8, 2q+9} (C rows 4q..4q+3 of each tile).
// Exact 16-step advance: z += 16dt*P - dtdt6*SV; P -= dt6*SB;
//   SB = sum B_j; SV = sum (15-j)B_j + sum A_j
//   V-partial = (15-j1)Bs - B2 - 8*B3 - 9*B4 + sumA;  2 bfly4 / 16 steps.
// Predictor in HORIZON-AGNOSTIC averaged form (bb = SB/H,
// aa = (SV - (H-1)/2*SB)/H, refreshed each exchange):
//   Pp_j  = P - j*dt6*bb
//   zp2_j = 2z + 2j*dt*P - dtdt6*j(j-1)*bb - 2j*dtdt6*aa     [2z form]
// (substitution-checked == R33's verified H=8 {SB,SV} coefficients).
// Stage lags zc/zd use own-step A_prev/3 (KC1n/KC2n folds, R33-verified).
// Cold start (zeros): dz ~ 6e-4 worst-j -> du ~ 1 f16 ulp (M ~ I+N(0,1/16),
// |u|~0.05) -- same benign class R29b absorbed bit-identically.
// S-identities: sp = uB, sq = uA; weights (99-n): uB1*cn + uB2*(cn-1) +
// uB3*(cn-8) + uB4*(cn-9); cn -= 16/exchange; tail cn = 3-j1 (checked).
// Tail (steps 96-99): tile0 only, quads 0,1 valid (vm mask), H=4 V-weight
// (3-j1); same averaged-predictor constants (horizon-agnostic).
// Race safety: R24 double-buffer argument; tail writes buf0 after
// barrier(e=5) (last buf0 reads were e=4, completed in-order pre-barrier).
//
// LDS: ubuf (2 x 32 rows x US = 34816 B) ALIASES wldsT post-M-build
// (R29c-verified pattern; wF0 in regs, epilogue wBt from GLOBAL W1 via
// the R29c-verified identical-conversion path). mscr separate. Total
// 135168 + 20480 = 155648 B (unchanged). R30 bank swizzle on ubuf
// (row chunk XOR ((row>>2)&3)<<3 via cw, odd-row ^32; tile1 = +16*US,
// same XOR family since (row+16)>>2 & 3 == row>>2 & 3).
// FULL unroll on every reg-array access (R4: dynamic index => scratch).
// Numerics: f16 storage (W, M, uA/uB, S), fp32 MFMA accum + fp32 z/P.
// Spill tripwire: WRITE_SIZE must stay ~512 KB (R29b lesson).

typedef _Float16 v8h __attribute__((ext_vector_type(8)));
typedef float v4f __attribute__((ext_vector_type(4)));

#define NFULL 6   // full 16-step exchanges; + 1 tail exchange of 4 steps
#define WS 264    // wldsT row stride (f16): row = one W-COLUMN, 16B-aligned
#define US 272    // ubuf row stride, f16 (544 B == 32 mod 128)

// D(+=C) in VGPRs, A (packed-vector frag) in VGPRs, B (M-frag) from AGPRs.
#define MFMA_AV(C, A, B) \
    asm("v_mfma_f32_16x16x32_f16 %0, %1, %2, %0" : "+v"(C) : "v"(A), "a"(B))

// 4-group butterfly sum over lanes {l, l^16, l^32, l^48}, pure VALU.
__device__ __forceinline__ float bfly4(float x) {
    float a = x, b = x;
    asm("v_permlane16_swap_b32 %0, %1" : "+v"(a), "+v"(b));
    float s = a + b;
    float c = s, d = s;
    asm("v_permlane32_swap_b32 %0, %1" : "+v"(c), "+v"(d));
    return c + d;
}

// u/(4*w2) eval on pre-doubled arg zz = 2*z:  r = rcp(e^zz + 1);
// u = 4*w2*(r - r^2)  ==  (1 - tanh^2(z)) * w2  exactly in algebra.
__device__ __forceinline__ float ueval2(float zz, float w4) {
    float e_ = __expf(zz);
    float r_ = __builtin_amdgcn_rcpf(e_ + 1.f);   // vs IEEE div: ~1e-7 rel
    return w4 * __builtin_fmaf(-r_, r_, r_);
}

// one step's 4 stage-z's + 4 u-evals + combo fold (averaged predictor)
__device__ __forceinline__ void stage_eval(
    float z1d, float P, float bb, float aa,
    float KPn, float K2j, float KZBn, float KZAn, float AL,
    float K2hdt, float K2dt, float KC1n, float KC2n, float w4,
    float& uA, float& uB)
{
    float Pp  = __builtin_fmaf(KPn, bb, P);
    float zp2 = __builtin_fmaf(K2j, P, z1d);
    zp2 = __builtin_fmaf(KZBn, bb, zp2);
    zp2 = __builtin_fmaf(KZAn, aa, zp2);
    float zb2 = __builtin_fmaf(K2hdt, Pp, zp2);
    float zc2 = __builtin_fmaf(KC1n, AL, zb2);
    float zd2 = __builtin_fmaf(K2dt, Pp, zp2);
    zd2 = __builtin_fmaf(KC2n, AL, zd2);
    float ua = ueval2(zp2, w4), ub = ueval2(zb2, w4);
    float uc = ueval2(zc2, w4), ud = ueval2(zd2, w4);
    float tv = ub + uc;
    uA = ua + tv;
    uB = __builtin_fmaf(2.f, tv, ua + ud);
}

__global__ __launch_bounds__(1024, 4)
void ham_kernel(const float* __restrict__ x0, const float* __restrict__ W1,
                const float* __restrict__ b1, const float* __restrict__ W2,
                float* __restrict__ out)
{
    __shared__ __align__(128) _Float16 wldsT[256 * WS];  // 135168 B: W^T (f16)
    __shared__ __align__(16)  float    mscr[16 * 320];   // 20480 B: M scratch
    _Float16* ubuf = wldsT;   // ALIAS: wldsT dead after M-build (wF0 in
                              // regs, epilogue wBt from global). R29c-proven.

    const int t = threadIdx.x;
    const int w = t >> 6;          // wave 0..15: owns tile w (16 comps)
    const int l = t & 63;
    const int quad = l >> 4;       // owns steps 2q, 2q+1, 2q+8, 2q+9
    const int s = l & 15;          // owned column / A-row
    const int c0 = 16 * w + s;     // owned component
    const int blk = blockIdx.x;
    const int kq = 8 * quad;
    const int sel = (s & 3) * US;  // prologue/epilogue A-row select (rows 0-3)

    // ---- stage W^T -> LDS f16: wldsT[c][r] = W[r][c] ----
    {
        const int c = t & 255;
        const int rbase = (t >> 8) * 64;   // 4 quarters x 64 rows
        #pragma unroll 1
        for (int r0 = 0; r0 < 64; r0 += 8) {
            v8h h;
            #pragma unroll
            for (int j = 0; j < 8; ++j)
                h[j] = (_Float16)W1[(rbase + r0 + j) * 256 + c];
            *(v8h*)(wldsT + c * WS + rbase + r0) = h;   // b128, one-time
        }
    }
    __syncthreads();

    // ---- wF: own-column W^T frag (B-op), contiguous b128 from wldsT ----
    v8h wF0[8];
    #pragma unroll
    for (int kk = 0; kk < 8; ++kk)
        wF0[kk] = *(const v8h*)(wldsT + c0 * WS + 32 * kk + kq);

    // ---- build M = W^T W column-block frags wM0 (B-op: M[k][c0]) ----
    v8h wM0[8];
    float* scr0 = mscr + w * 320;
    #pragma unroll
    for (int kb = 0; kb < 16; ++kb) {
        v8h aM[8];   // A[m=s][k=8quad+j] = wldsT[(16kb+s)*WS + 32kk+kq+j]
        #pragma unroll
        for (int kk = 0; kk < 8; ++kk)
            aM[kk] = *(const v8h*)(wldsT + (16 * kb + s) * WS + 32 * kk + kq);
        v4f D0 = {0.f,0.f,0.f,0.f};
        #pragma unroll
        for (int kk = 0; kk < 8; ++kk)
            D0 = __builtin_amdgcn_mfma_f32_16x16x32_f16(aM[kk], wF0[kk], D0, 0, 0, 0);
        *(v4f*)(scr0 + s * 20 + 4 * quad) = D0;
        asm volatile("s_waitcnt lgkmcnt(0)" ::: "memory");  // in-wave x-lane
        if ((quad >> 1) == (kb & 1)) {
            #pragma unroll
            for (int j = 0; j < 8; ++j)
                wM0[kb >> 1][j] = (_Float16)scr0[s * 20 + 8 * (quad & 1) + j];
        }
        asm volatile("s_waitcnt lgkmcnt(0)" ::: "memory");
    }
    __syncthreads();   // all wldsT/mscr reads done -> ubuf may reuse wldsT

    const float b1r0 = b1[c0];
    const float w4 = 4.f * W2[c0];
    float2 qp0 = ((const float2*)(x0 + (size_t)blk * 512))[c0];
    const float q0o0 = qp0.x, p0o0 = qp0.y;

    // ---- prologue: buf0 rows {q0, p0, 0, 0} -> z1 (C[0]), P (C[1]) ----
    if (quad == 0) {
        ubuf[c0] = (_Float16)q0o0;
        ubuf[US + c0] = (_Float16)p0o0;
        ubuf[2 * US + c0] = (_Float16)0.f;
        ubuf[3 * US + c0] = (_Float16)0.f;
    }
    __syncthreads();
    float z1, P;
    {
        const _Float16* ab = ubuf + sel + kq;
        v4f C0a = {0.f,0.f,0.f,0.f}, C0b = {0.f,0.f,0.f,0.f};
        #pragma unroll
        for (int kk = 0; kk < 8; kk += 2) {
            v8h a0 = *(const v8h*)(ab + 32 * kk);
            v8h a1 = *(const v8h*)(ab + 32 * (kk + 1));
            C0a = __builtin_amdgcn_mfma_f32_16x16x32_f16(a0, wF0[kk], C0a, 0, 0, 0);
            C0b = __builtin_amdgcn_mfma_f32_16x16x32_f16(a1, wF0[kk + 1], C0b, 0, 0, 0);
        }
        v4f C0s = C0a + C0b;
        z1 = C0s[0] + b1r0;  P = C0s[1];
    }
    __syncthreads();   // prologue reads done before u(0) overwrites buf0

    const float dt = 0.01f, hdt = 0.005f, dt6 = 0.01f / 6.f;
    const float dtdt6 = dt * dt6, hdt2 = hdt * hdt, dthdt = dt * hdt;
    const float K16dt = 16.f * dt, K4dt = 4.f * dt;
    const float K2hdt = 2.f * hdt, K2dt = 2.f * dt;
    const float KC1n = -(2.f * hdt2) / 3.f;   // zc: -2hdt^2 * (A/3) folded
    const float KC2n = -(2.f * dthdt) / 3.f;  // zd: -2*dt*hdt* (A/3) folded
    // owned steps j1=2q, j2=j1+1, j3=j1+8, j4=j1+9; averaged-form coefs:
    //   KPn = -j*dt6; K2j = 2j*dt; KZBn = -dtdt6*j*(j-1); KZAn = -2j*dtdt6
    const float j1 = 2.f * (float)quad, j2 = j1 + 1.f;
    const float j3 = j1 + 8.f,          j4 = j1 + 9.f;
    const float KPn1 = -j1 * dt6, KPn2 = -j2 * dt6;
    const float KPn3 = -j3 * dt6, KPn4 = -j4 * dt6;
    const float K2j1 = 2.f * j1 * dt, K2j2 = 2.f * j2 * dt;
    const float K2j3 = 2.f * j3 * dt, K2j4 = 2.f * j4 * dt;
    const float KZB1 = -dtdt6 * j1 * (j1 - 1.f), KZB2 = -dtdt6 * j2 * (j2 - 1.f);
    const float KZB3 = -dtdt6 * j3 * (j3 - 1.f), KZB4 = -dtdt6 * j4 * (j4 - 1.f);
    const float KZA1 = -2.f * j1 * dtdt6, KZA2 = -2.f * j2 * dtdt6;
    const float KZA3 = -2.f * j3 * dtdt6, KZA4 = -2.f * j4 * dtdt6;
    const float w15 = 15.f - j1;              // main V weight
    const float w3  = 3.f - j1;               // tail H=4 V weight

    // ---- ubuf addressing (R30/R33 bank swizzle; tile1 = +16*US) ----
    const int cw = c0 ^ (quad << 3);
    const int R0 = 4 * quad;
    const int wo0 = (R0 + 0) * US + cw;          // row 4q   = uA(j1)
    const int wo1 = (R0 + 1) * US + (cw ^ 32);   // row 4q+1 = uB(j1)
    const int wo2 = (R0 + 2) * US + cw;          // row 4q+2 = uA(j2)
    const int wo3 = (R0 + 3) * US + (cw ^ 32);   // row 4q+3 = uB(j2)
    const int sx = (s >> 2) & 3;
    const int rbas = s * US + 8 * (quad ^ sx);
    const int sodd = (s & 1) << 5;
    const _Float16* pe = ubuf + rbas + sodd;          // logical even kk
    const _Float16* po = ubuf + rbas + 32 - sodd;     // logical odd  kk

    // lag state (exchange 0: zeros -> benign cold start, analyzed above)
    float bb = 0.f, aa = 0.f;
    float AL1 = 0.f, AL2 = 0.f, AL3 = 0.f, AL4 = 0.f;
    float S1p = 0.f, S23p = 0.f;
    float cn = 99.f - j1;          // weight of uB(j1) this exchange

    #pragma unroll 1
    for (int e = 0; e < NFULL; ++e) {
        const int bo = (e & 1) * (32 * US);   // double-buffer offset

        // ---- 4 owned steps: 16 u-evals -> 8 combos; 8 ds_writes ----
        float z1d = z1 + z1;
        float uA1, uB1, uA2, uB2, uA3, uB3, uA4, uB4;
        stage_eval(z1d, P, bb, aa, KPn1, K2j1, KZB1, KZA1, AL1,
                   K2hdt, K2dt, KC1n, KC2n, w4, uA1, uB1);
        stage_eval(z1d, P, bb, aa, KPn2, K2j2, KZB2, KZA2, AL2,
                   K2hdt, K2dt, KC1n, KC2n, w4, uA2, uB2);
        stage_eval(z1d, P, bb, aa, KPn3, K2j3, KZB3, KZA3, AL3,
                   K2hdt, K2dt, KC1n, KC2n, w4, uA3, uB3);
        stage_eval(z1d, P, bb, aa, KPn4, K2j4, KZB4, KZA4, AL4,
                   K2hdt, K2dt, KC1n, KC2n, w4, uA4, uB4);

        ubuf[bo + wo0] = (_Float16)uA1;
        ubuf[bo + wo1] = (_Float16)uB1;
        ubuf[bo + wo2] = (_Float16)uA2;
        ubuf[bo + wo3] = (_Float16)uB2;
        ubuf[bo + wo0 + 16 * US] = (_Float16)uA3;
        ubuf[bo + wo1 + 16 * US] = (_Float16)uB3;
        ubuf[bo + wo2 + 16 * US] = (_Float16)uA4;
        ubuf[bo + wo3 + 16 * US] = (_Float16)uB4;
        __syncthreads();   // the ONLY barrier per exchange (16 steps)

        // ---- TWO MFMA blocks: tile0 -> {A1,B1,A2,B2}, tile1 -> {A3..B4} ----
        v4f C0s, C1s;
        {
            v4f C0a = {0.f,0.f,0.f,0.f}, C0b = {0.f,0.f,0.f,0.f};
            v4f C1a = {0.f,0.f,0.f,0.f}, C1b = {0.f,0.f,0.f,0.f};
            #pragma unroll
            for (int kk = 0; kk < 8; kk += 2) {
                v8h a0 = *(const v8h*)(pe + bo + 32 * kk);
                v8h a1 = *(const v8h*)(po + bo + 32 * kk);
                v8h a2 = *(const v8h*)(pe + bo + 32 * kk + 16 * US);
                v8h a3 = *(const v8h*)(po + bo + 32 * kk + 16 * US);
                MFMA_AV(C0a, a0, wM0[kk]);
                MFMA_AV(C1a, a2, wM0[kk]);
                MFMA_AV(C0b, a1, wM0[kk + 1]);
                MFMA_AV(C1b, a3, wM0[kk + 1]);
            }
            C0s = C0a + C0b;  C1s = C1a + C1b;
        }
        // no second barrier: next exchange writes the OTHER buffer (R24).

        // ---- EXACT 16-step advance via 2 butterflies ----
        float A1 = C0s[0], B1 = C0s[1], A2 = C0s[2], B2 = C0s[3];
        float A3 = C1s[0], B3 = C1s[1], A4 = C1s[2], B4 = C1s[3];
        float Bs = (B1 + B2) + (B3 + B4);
        float tV = (A1 + A2) + (A3 + A4) - B2;
        tV = __builtin_fmaf(-8.f, B3, tV);
        tV = __builtin_fmaf(-9.f, B4, tV);
        float V  = __builtin_fmaf(w15, Bs, tV);   // sum (15-j)B_j + sum A_j
        float SB = bfly4(Bs);
        float SV = bfly4(V);

        z1 = __builtin_fmaf(K16dt, P, z1);     // z += 16dt*P (old P)
        z1 = __builtin_fmaf(-dtdt6, SV, z1);
        P  = __builtin_fmaf(-dt6, SB, P);

        bb = SB * 0.0625f;                              // SB/16
        aa = __builtin_fmaf(-7.5f, SB, SV) * 0.0625f;   // (SV-7.5SB)/16
        AL1 = A1;  AL2 = A2;  AL3 = A3;  AL4 = A4;

        // ---- S partials (identities sp=uB, sq=uA, pre-f16 f32) ----
        S1p += (uB1 + uB2) + (uB3 + uB4);
        S23p = __builtin_fmaf(cn, uB1, S23p) + uA1;
        S23p = __builtin_fmaf(cn - 1.f, uB2, S23p) + uA2;
        S23p = __builtin_fmaf(cn - 8.f, uB3, S23p) + uA3;
        S23p = __builtin_fmaf(cn - 9.f, uB4, S23p) + uA4;
        cn -= 16.f;
    }

    // ---- tail: steps 96-99, buf0, tile0 only; quads 0,1 valid (vm) ----
    {
        const float vm = (quad < 2) ? 1.f : 0.f;
        float z1d = z1 + z1;
        float uA1, uB1, uA2, uB2;
        stage_eval(z1d, P, bb, aa, KPn1, K2j1, KZB1, KZA1, AL1,
                   K2hdt, K2dt, KC1n, KC2n, w4, uA1, uB1);
        stage_eval(z1d, P, bb, aa, KPn2, K2j2, KZB2, KZA2, AL2,
                   K2hdt, K2dt, KC1n, KC2n, w4, uA2, uB2);
        uA1 *= vm;  uB1 *= vm;  uA2 *= vm;  uB2 *= vm;

        ubuf[wo0] = (_Float16)uA1;
        ubuf[wo1] = (_Float16)uB1;
        ubuf[wo2] = (_Float16)uA2;
        ubuf[wo3] = (_Float16)uB2;
        __syncthreads();

        v4f C0s;
        {
            v4f C0a = {0.f,0.f,0.f,0.f}, C0b = {0.f,0.f,0.f,0.f};
            #pragma unroll
            for (int kk = 0; kk < 8; kk += 2) {
                v8h a0 = *(const v8h*)(pe + 32 * kk);
                v8h a1 = *(const v8h*)(po + 32 * kk);
                MFMA_AV(C0a, a0, wM0[kk]);
                MFMA_AV(C0b, a1, wM0[kk + 1]);
            }
            C0s = C0a + C0b;
        }
        float A1 = C0s[0], B1 = C0s[1], A2 = C0s[2], B2 = C0s[3];
        float Bs = B1 + B2;
        float V  = __builtin_fmaf(w3, Bs, A1 + A2 - B2);  // (3-j1)B1+(3-j2)B2+A
        float SB = bfly4(Bs);
        float SV = bfly4(V);
        z1 = __builtin_fmaf(K4dt, P, z1);
        z1 = __builtin_fmaf(-dtdt6, SV, z1);
        P  = __builtin_fmaf(-dt6, SB, P);
        S1p += uB1 + uB2;                       // cn = 3-j1 here (checked)
        S23p = __builtin_fmaf(cn, uB1, S23p) + uA1;
        S23p = __builtin_fmaf(cn - 1.f, uB2, S23p) + uA2;
    }

    // ---- epilogue: reduce S; buf0 rows {S1, S23, 0, 0} ----
    const float S1f  = bfly4(S1p);
    const float S23f = bfly4(S23p);
    __syncthreads();   // tail's buf0 reads done before overwrite
    if (quad == 0) {
        ubuf[c0] = (_Float16)S1f;
        ubuf[US + c0] = (_Float16)S23f;
        ubuf[2 * US + c0] = (_Float16)0.f;
        ubuf[3 * US + c0] = (_Float16)0.f;
    }
    __syncthreads();
    // wBt from GLOBAL W1 (contiguous; same f32->f16 as staging; R29c path)
    v8h wBt0[8];
    #pragma unroll
    for (int kk = 0; kk < 8; ++kk) {
        const float* wp = W1 + c0 * 256 + 32 * kk + kq;
        v4f lo = *(const v4f*)(wp);
        v4f hi = *(const v4f*)(wp + 4);
        v8h h;
        h[0] = (_Float16)lo[0]; h[1] = (_Float16)lo[1];
        h[2] = (_Float16)lo[2]; h[3] = (_Float16)lo[3];
        h[4] = (_Float16)hi[0]; h[5] = (_Float16)hi[1];
        h[6] = (_Float16)hi[2]; h[7] = (_Float16)hi[3];
        wBt0[kk] = h;
    }
    float D10, D20;
    {
        const _Float16* ab = ubuf + sel + kq;
        v4f C0a = {0.f,0.f,0.f,0.f}, C0b = {0.f,0.f,0.f,0.f};
        #pragma unroll
        for (int kk = 0; kk < 8; kk += 2) {
            v8h a0 = *(const v8h*)(ab + 32 * kk);
            v8h a1 = *(const v8h*)(ab + 32 * (kk + 1));
            C0a = __builtin_amdgcn_mfma_f32_16x16x32_f16(a0, wBt0[kk], C0a, 0, 0, 0);
            C0b = __builtin_amdgcn_mfma_f32_16x16x32_f16(a1, wBt0[kk + 1], C0b, 0, 0, 0);
        }
        v4f C0s = C0a + C0b;
        D10 = C0s[0];  D20 = C0s[1];
    }
    const float dt6e = 0.01f / 6.f, dtdt6e = 0.01f * dt6e;
    float pT0 = p0o0 - dt6e * D10;
    float qT0 = q0o0 + 0.01f * 100.f * p0o0 - dtdt6e * D20;

    if (quad == 0)
        ((float2*)(out + (size_t)blk * 512))[c0] = make_float2(qT0, pT0);
}

extern "C" void kernel_launch(void* const* d_in, const int* in_sizes, int n_in,
                              void* d_out, int out_size, void* d_ws, size_t ws_size,
                              hipStream_t stream) {
    const float* x0 = (const float*)d_in[0];
    const float* W1 = (const float*)d_in[1];
    const float* b1 = (const float*)d_in[2];
    const float* W2 = (const float*)d_in[3];
    // d_in[4] = b2: constant offset, no effect on the gradient/dynamics.
    float* out = (float*)d_out;
    hipLaunchKernelGGL(ham_kernel, dim3(256), dim3(1024), 0, stream,
                       x0, W1, b1, W2, out);
}

// Round 13
// 92.351 us; speedup vs baseline: 1.0646x; 1.0646x over previous
//
#include <hip/hip_runtime.h>
#include <stdint.h>

// HamiltonianFlow: x [256, 8, 32, 2] (q,p); H = 0.5*sum(p^2) + MLP(q).
// dq/dt = p, dp/dt = -W u(z), z = W^T q + b1, u = (1-tanh^2(z)).*W2.
// z-space iteration with M = W^T W (R15-R23 verified).
//
// R35 = R33 (measured best: 40.5us, bit-identical absmax) + DEAD-TAIL
// ELIMINATION. R34 (16-step exchanges) regressed 40.5->44.5: per-exchange
// interiors serialize superlinearly when doubled; the exchange-count curve
// 25->46.8, 13->40.5, 7->44.5 pins H=8 as the optimum. Revert to R33.
// New cut: the tail exchange (steps 96-99) feeds ONLY the S-sums, which
// are accumulated per-lane from the u-evals BEFORE any LDS write. Its
// ds-writes, barrier, MFMA, butterflies and state advance produce values
// (z1,P past step 100) that nothing downstream reads (epilogue uses only
// q0,p0,S1,S23). Tail := 2 predictor stage-evals + masked S-adds. Saves
// one full exchange interval (~6.8k cyc); S path arithmetic unchanged =>
// bit-identical output to R33.
//
// R33 recap: COMBO-LINEARITY - the advance/predictor need only
// A_j = Y1+Y2+Y3, B_j = Y1+2Y2+2Y3+Y4, and Y_i = M u_i => sum u's BEFORE
// the matvec: row(2j) = uA_j = ua+ub+uc; row(2j+1) = uB_j =
// ua+2ub+2uc+ud. 16 rows = 8 steps/exchange, 12 full exchanges.
// Exact 8-step advance: z += 8dt*P - dtdt6*SV8;  P -= dt6*SB8;
//   SB8 = sum B_j;  SV8 = sum (7-j)B_j + sum A_j
//   pred step j: Pp = P - (j/8)dt6*SBp;
//     zp2 = 2z + 2j*dt*P + dtdt6*j(8-j)/8*SBp - dtdt6*(j/4)*SVp
// Lane (quad q) owns steps j1=2q, j2=2q+1 (C rows 4q..4q+3 =
// {A_j1,B_j1,A_j2,B_j2} in-lane); V-partial = fma(7-j1, B1+B2, A1+A2-B2);
// 2 bfly4 per 8 steps. Stage-lags zc/zd use own-step A_prev/3 (KC1n/KC2n
// folds). S-identities: sp = uB, sq = uA (pre-f16 f32).
// Tail weights: cn1 after 12 exchanges = 99-j1-96 = 3-j1 (checked).
//
// R30 substrate: 16 waves x 1 tile (1024 thr), in-kernel W^T staging +
// M-build, ONE barrier per exchange (R24 double-buffer race argument),
// R30 bank-swizzle, permlane bfly4, exp-fold (2z chain) + rcp,
// mscr UNION ubuf (upool).
// FULL unroll on every reg-array access (R4: dynamic index => scratch).
// Numerics: f16 storage (W, M, uA/uB, S), fp32 MFMA accum + fp32 z/P.

typedef _Float16 v8h __attribute__((ext_vector_type(8)));
typedef float v4f __attribute__((ext_vector_type(4)));

#define NFULL 12  // full 8-step exchanges; steps 96-99 = eval-only tail
#define WS 264    // wldsT row stride (f16): row = one W-COLUMN, 16B-aligned
#define US 272    // ubuf row stride, f16 (544 B == 32 mod 128)

// D(+=C) in VGPRs, A (packed-vector frag) in VGPRs, B (M-frag) from AGPRs.
#define MFMA_AV(C, A, B) \
    asm("v_mfma_f32_16x16x32_f16 %0, %1, %2, %0" : "+v"(C) : "v"(A), "a"(B))

// 4-group butterfly sum over lanes {l, l^16, l^32, l^48}, pure VALU.
__device__ __forceinline__ float bfly4(float x) {
    float a = x, b = x;
    asm("v_permlane16_swap_b32 %0, %1" : "+v"(a), "+v"(b));
    float s = a + b;
    float c = s, d = s;
    asm("v_permlane32_swap_b32 %0, %1" : "+v"(c), "+v"(d));
    return c + d;
}

// u/(4*w2) eval on pre-doubled arg zz = 2*z:  r = rcp(e^zz + 1);
// u = 4*w2*(r - r^2)  ==  (1 - tanh^2(z)) * w2  exactly in algebra.
__device__ __forceinline__ float ueval2(float zz, float w4) {
    float e_ = __expf(zz);
    float r_ = __builtin_amdgcn_rcpf(e_ + 1.f);   // vs IEEE div: ~1e-7 rel
    return w4 * __builtin_fmaf(-r_, r_, r_);
}

__global__ __launch_bounds__(1024, 4)
void ham_kernel(const float* __restrict__ x0, const float* __restrict__ W1,
                const float* __restrict__ b1, const float* __restrict__ W2,
                float* __restrict__ out)
{
    __shared__ __align__(16)  _Float16 wldsT[256 * WS];  // 135168 B: W^T (f16)
    __shared__ __align__(128) char     upool[20480];     // mscr UNION ubuf
    float*    mscr = (float*)upool;                      // setup only
    _Float16* ubuf = (_Float16*)upool;                   // 2 x 16 rows x US

    const int t = threadIdx.x;
    const int w = t >> 6;          // wave 0..15: owns tile w (16 comps)
    const int l = t & 63;
    const int quad = l >> 4;       // owns steps 2*quad, 2*quad+1
    const int s = l & 15;          // owned column / A-row
    const int c0 = 16 * w + s;     // owned component
    const int blk = blockIdx.x;
    const int sel = (s & 3) * US;  // prologue/epilogue A-row select (rows 0-3)

    // ---- stage W^T -> LDS f16: wldsT[c][r] = W[r][c] ----
    {
        const int c = t & 255;
        const int rbase = (t >> 8) * 64;   // 4 quarters x 64 rows
        #pragma unroll 1
        for (int r0 = 0; r0 < 64; r0 += 8) {
            v8h h;
            #pragma unroll
            for (int j = 0; j < 8; ++j)
                h[j] = (_Float16)W1[(rbase + r0 + j) * 256 + c];
            *(v8h*)(wldsT + c * WS + rbase + r0) = h;   // b128, one-time
        }
    }
    __syncthreads();

    // ---- wF: own-column W^T frag (B-op), contiguous b128 from wldsT ----
    v8h wF0[8];
    #pragma unroll
    for (int kk = 0; kk < 8; ++kk)
        wF0[kk] = *(const v8h*)(wldsT + c0 * WS + 32 * kk + 8 * quad);

    // ---- build M = W^T W column-block frags wM0 (B-op: M[k][c0]) ----
    v8h wM0[8];
    float* scr0 = mscr + w * 320;
    #pragma unroll
    for (int kb = 0; kb < 16; ++kb) {
        v8h aM[8];   // A[m=s][k=8quad+j] = wldsT[(16kb+s)*WS + 32kk+8quad+j]
        #pragma unroll
        for (int kk = 0; kk < 8; ++kk)
            aM[kk] = *(const v8h*)(wldsT + (16 * kb + s) * WS
                                          + 32 * kk + 8 * quad);
        v4f D0 = {0.f,0.f,0.f,0.f};
        #pragma unroll
        for (int kk = 0; kk < 8; ++kk)
            D0 = __builtin_amdgcn_mfma_f32_16x16x32_f16(aM[kk], wF0[kk], D0, 0, 0, 0);
        *(v4f*)(scr0 + s * 20 + 4 * quad) = D0;
        asm volatile("s_waitcnt lgkmcnt(0)" ::: "memory");  // in-wave x-lane
        if ((quad >> 1) == (kb & 1)) {
            #pragma unroll
            for (int j = 0; j < 8; ++j)
                wM0[kb >> 1][j] = (_Float16)scr0[s * 20 + 8 * (quad & 1) + j];
        }
        asm volatile("s_waitcnt lgkmcnt(0)" ::: "memory");
    }
    __syncthreads();   // mscr reads (all waves) done before ubuf reuse

    const float b1r0 = b1[c0];
    const float w4 = 4.f * W2[c0];
    float2 qp0 = ((const float2*)(x0 + (size_t)blk * 512))[c0];
    const float q0o0 = qp0.x, p0o0 = qp0.y;

    // ---- prologue: buf0 rows {q0, p0, 0, 0} -> z1 (C[0]), P (C[1]) ----
    if (quad == 0) {
        ubuf[c0] = (_Float16)q0o0;
        ubuf[US + c0] = (_Float16)p0o0;
        ubuf[2 * US + c0] = (_Float16)0.f;
        ubuf[3 * US + c0] = (_Float16)0.f;
    }
    __syncthreads();
    float z1, P;
    {
        const _Float16* ab = ubuf + sel + 8 * quad;
        v4f C0a = {0.f,0.f,0.f,0.f}, C0b = {0.f,0.f,0.f,0.f};
        #pragma unroll
        for (int kk = 0; kk < 8; kk += 2) {
            v8h a0 = *(const v8h*)(ab + 32 * kk);
            v8h a1 = *(const v8h*)(ab + 32 * (kk + 1));
            C0a = __builtin_amdgcn_mfma_f32_16x16x32_f16(a0, wF0[kk], C0a, 0, 0, 0);
            C0b = __builtin_amdgcn_mfma_f32_16x16x32_f16(a1, wF0[kk + 1], C0b, 0, 0, 0);
        }
        v4f C0s = C0a + C0b;
        z1 = C0s[0] + b1r0;  P = C0s[1];
    }
    __syncthreads();   // prologue reads done before u(0) overwrites buf0

    const float dt = 0.01f, hdt = 0.005f, dt6 = 0.01f / 6.f;
    const float dtdt6 = dt * dt6, hdt2 = hdt * hdt, dthdt = dt * hdt;
    const float K8dt = 8.f * dt;
    // steps j1 = 2q, j2 = 2q+1; horizon-8 predictor coefs (R29c-verified)
    const float j1 = 2.f * (float)quad, j2 = j1 + 1.f;
    const float cPn1 = -(j1 * 0.125f * dt6), cPn2 = -(j2 * 0.125f * dt6);
    const float Kz1a = 2.f * j1 * dt,        Kz1b = 2.f * j2 * dt;
    const float KB1 = dtdt6 * j1 * (8.f - j1) * 0.125f;
    const float KB2 = dtdt6 * j2 * (8.f - j2) * 0.125f;
    const float KVn1 = -(j1 * dtdt6 * 0.25f), KVn2 = -(j2 * dtdt6 * 0.25f);
    const float K2hdt = 2.f * hdt;
    const float K2dt  = 2.f * dt;
    const float KC1n = -(2.f * hdt2) / 3.f;   // zc: -2hdt^2 * (A/3) folded
    const float KC2n = -(2.f * dthdt) / 3.f;  // zd: -2*dt*hdt * (A/3) folded
    const float w71 = 7.f - j1;               // V = fma(w71, B1+B2, A1+A2-B2)

    // ---- ubuf addressing (R30 bank swizzle, kept) ----
    const int cw = c0 ^ (quad << 3);
    const int R0 = 4 * quad;
    const int wo0 = (R0 + 0) * US + cw;          // row 4q   = uA(j1)
    const int wo1 = (R0 + 1) * US + (cw ^ 32);   // row 4q+1 = uB(j1)
    const int wo2 = (R0 + 2) * US + cw;          // row 4q+2 = uA(j2)
    const int wo3 = (R0 + 3) * US + (cw ^ 32);   // row 4q+3 = uB(j2)
    const int sx = (s >> 2) & 3;
    const int rbase = s * US + 8 * (quad ^ sx);
    const int sodd = (s & 1) << 5;
    const _Float16* pe = ubuf + rbase + sodd;          // logical even kk
    const _Float16* po = ubuf + rbase + 32 - sodd;     // logical odd  kk

    // lag state (exchange 0: zeros -> benign one-time transient)
    float SBp = 0.f, SVp = 0.f;
    float AL1 = 0.f, AL2 = 0.f;    // own-step A-combo lags (Y1~Y2~A/3)
    float S1p = 0.f, S23p = 0.f;
    float cn1 = 99.f - j1;         // step n1 = 8e + j1; n2 = n1 + 1

    #pragma unroll 1
    for (int e = 0; e < NFULL; ++e) {
        const int bo = (e & 1) * (16 * US);   // double-buffer offset

        // ---- predict both steps; 8 stage-z's; 8 u evals; 4 combos ----
        float z1d = z1 + z1;
        float Pp1  = __builtin_fmaf(cPn1, SBp, P);
        float zp21 = __builtin_fmaf(Kz1a, P, z1d);
        zp21 = __builtin_fmaf(KB1, SBp, zp21);
        zp21 = __builtin_fmaf(KVn1, SVp, zp21);
        float zb21 = __builtin_fmaf(K2hdt, Pp1, zp21);
        float zc21 = __builtin_fmaf(KC1n, AL1, zb21);
        float zd21 = __builtin_fmaf(K2dt, Pp1, zp21);
        zd21 = __builtin_fmaf(KC2n, AL1, zd21);
        float Pp2  = __builtin_fmaf(cPn2, SBp, P);
        float zp22 = __builtin_fmaf(Kz1b, P, z1d);
        zp22 = __builtin_fmaf(KB2, SBp, zp22);
        zp22 = __builtin_fmaf(KVn2, SVp, zp22);
        float zb22 = __builtin_fmaf(K2hdt, Pp2, zp22);
        float zc22 = __builtin_fmaf(KC1n, AL2, zb22);
        float zd22 = __builtin_fmaf(K2dt, Pp2, zp22);
        zd22 = __builtin_fmaf(KC2n, AL2, zd22);

        float ua1 = ueval2(zp21, w4), ub1 = ueval2(zb21, w4);
        float uc1 = ueval2(zc21, w4), ud1 = ueval2(zd21, w4);
        float ua2 = ueval2(zp22, w4), ub2 = ueval2(zb22, w4);
        float uc2 = ueval2(zc22, w4), ud2 = ueval2(zd22, w4);

        float tv1 = ub1 + uc1;
        float uA1 = ua1 + tv1;                                // = sq(j1)
        float uB1 = __builtin_fmaf(2.f, tv1, ua1 + ud1);      // = sp(j1)
        float tv2 = ub2 + uc2;
        float uA2 = ua2 + tv2;
        float uB2 = __builtin_fmaf(2.f, tv2, ua2 + ud2);

        ubuf[bo + wo0] = (_Float16)uA1;
        ubuf[bo + wo1] = (_Float16)uB1;
        ubuf[bo + wo2] = (_Float16)uA2;
        ubuf[bo + wo3] = (_Float16)uB2;
        __syncthreads();   // the ONLY barrier per exchange (8 steps)

        // ---- ONE MFMA block: {A1,B1,A2,B2} combos for own comp ----
        v4f C0s;
        {
            v4f C0a = {0.f,0.f,0.f,0.f}, C0b = {0.f,0.f,0.f,0.f};
            #pragma unroll
            for (int kk = 0; kk < 8; kk += 2) {
                v8h a0 = *(const v8h*)(pe + bo + 32 * kk);
                v8h a1 = *(const v8h*)(po + bo + 32 * kk);
                MFMA_AV(C0a, a0, wM0[kk]);
                MFMA_AV(C0b, a1, wM0[kk + 1]);
            }
            C0s = C0a + C0b;
        }
        // no second barrier: next exchange writes the OTHER buffer (R24).

        // ---- EXACT 8-step advance via 2 butterflies ----
        float A1 = C0s[0], B1 = C0s[1], A2 = C0s[2], B2 = C0s[3];
        float Bs = B1 + B2;
        float V  = __builtin_fmaf(w71, Bs, A1 + A2 - B2);  // (7-j1)B1+(7-j2)B2+A1+A2
        float SB = bfly4(Bs);
        float SV = bfly4(V);

        z1 = __builtin_fmaf(K8dt, P, z1);      // z += 8dt*P (old P)
        z1 = __builtin_fmaf(-dtdt6, SV, z1);
        P  = __builtin_fmaf(-dt6, SB, P);

        SBp = SB;  SVp = SV;  AL1 = A1;  AL2 = A2;   // lag state

        // ---- S partials (identities sp=uB, sq=uA, pre-f16 f32) ----
        S1p += uB1 + uB2;
        S23p = __builtin_fmaf(cn1, uB1, S23p) + uA1;
        S23p = __builtin_fmaf(cn1 - 1.f, uB2, S23p) + uA2;
        cn1 -= 8.f;
    }

    // ---- tail, steps 96-99: S-ONLY. The tail's LDS write / barrier /
    //      MFMA / bfly / advance are DEAD (post-step-100 z,P unused;
    //      S-adds consume the per-lane pre-f16 u's directly). Same eval
    //      formulas + vm mask as R33's tail => bit-identical S. ----
    {
        const float vm = (quad < 2) ? 1.f : 0.f;
        float z1d = z1 + z1;
        float Pp1  = __builtin_fmaf(cPn1, SBp, P);
        float zp21 = __builtin_fmaf(Kz1a, P, z1d);
        zp21 = __builtin_fmaf(KB1, SBp, zp21);
        zp21 = __builtin_fmaf(KVn1, SVp, zp21);
        float zb21 = __builtin_fmaf(K2hdt, Pp1, zp21);
        float zc21 = __builtin_fmaf(KC1n, AL1, zb21);
        float zd21 = __builtin_fmaf(K2dt, Pp1, zp21);
        zd21 = __builtin_fmaf(KC2n, AL1, zd21);
        float Pp2  = __builtin_fmaf(cPn2, SBp, P);
        float zp22 = __builtin_fmaf(Kz1b, P, z1d);
        zp22 = __builtin_fmaf(KB2, SBp, zp22);
        zp22 = __builtin_fmaf(KVn2, SVp, zp22);
        float zb22 = __builtin_fmaf(K2hdt, Pp2, zp22);
        float zc22 = __builtin_fmaf(KC1n, AL2, zb22);
        float zd22 = __builtin_fmaf(K2dt, Pp2, zp22);
        zd22 = __builtin_fmaf(KC2n, AL2, zd22);

        float ua1 = ueval2(zp21, w4), ub1 = ueval2(zb21, w4);
        float uc1 = ueval2(zc21, w4), ud1 = ueval2(zd21, w4);
        float ua2 = ueval2(zp22, w4), ub2 = ueval2(zb22, w4);
        float uc2 = ueval2(zc22, w4), ud2 = ueval2(zd22, w4);

        float tv1 = ub1 + uc1;
        float uA1 = (ua1 + tv1) * vm;
        float uB1 = __builtin_fmaf(2.f, tv1, ua1 + ud1) * vm;
        float tv2 = ub2 + uc2;
        float uA2 = (ua2 + tv2) * vm;
        float uB2 = __builtin_fmaf(2.f, tv2, ua2 + ud2) * vm;

        S1p += uB1 + uB2;                       // cn1 = 3-j1 here (checked)
        S23p = __builtin_fmaf(cn1, uB1, S23p) + uA1;
        S23p = __builtin_fmaf(cn1 - 1.f, uB2, S23p) + uA2;
    }

    // ---- epilogue: reduce S over quads; buf0 rows {S1, S23, 0, 0} ----
    const float S1f  = bfly4(S1p);
    const float S23f = bfly4(S23p);
    __syncthreads();   // all waves past loop (e=10 buf0-reads complete)
    if (quad == 0) {
        ubuf[c0] = (_Float16)S1f;
        ubuf[US + c0] = (_Float16)S23f;
        ubuf[2 * US + c0] = (_Float16)0.f;
        ubuf[3 * US + c0] = (_Float16)0.f;
    }
    __syncthreads();
    // wBt[kk][j] = W[c0][32kk+8quad+j] = wldsT[(32kk+8quad+j)*WS + c0]
    v8h wBt0[8];
    #pragma unroll
    for (int kk = 0; kk < 8; ++kk)
        #pragma unroll
        for (int j = 0; j < 8; ++j)
            wBt0[kk][j] = wldsT[(32 * kk + 8 * quad + j) * WS + c0];
    float D10, D20;
    {
        const _Float16* ab = ubuf + sel + 8 * quad;
        v4f C0a = {0.f,0.f,0.f,0.f}, C0b = {0.f,0.f,0.f,0.f};
        #pragma unroll
        for (int kk = 0; kk < 8; kk += 2) {
            v8h a0 = *(const v8h*)(ab + 32 * kk);
            v8h a1 = *(const v8h*)(ab + 32 * (kk + 1));
            C0a = __builtin_amdgcn_mfma_f32_16x16x32_f16(a0, wBt0[kk], C0a, 0, 0, 0);
            C0b = __builtin_amdgcn_mfma_f32_16x16x32_f16(a1, wBt0[kk + 1], C0b, 0, 0, 0);
        }
        v4f C0s = C0a + C0b;
        D10 = C0s[0];  D20 = C0s[1];
    }
    const float dt6e = 0.01f / 6.f, dtdt6e = 0.01f * dt6e;
    float pT0 = p0o0 - dt6e * D10;
    float qT0 = q0o0 + 0.01f * 100.f * p0o0 - dtdt6e * D20;

    if (quad == 0)
        ((float2*)(out + (size_t)blk * 512))[c0] = make_float2(qT0, pT0);
}

extern "C" void kernel_launch(void* const* d_in, const int* in_sizes, int n_in,
                              void* d_out, int out_size, void* d_ws, size_t ws_size,
                              hipStream_t stream) {
    const float* x0 = (const float*)d_in[0];
    const float* W1 = (const float*)d_in[1];
    const float* b1 = (const float*)d_in[2];
    const float* W2 = (const float*)d_in[3];
    // d_in[4] = b2: constant offset, no effect on the gradient/dynamics.
    float* out = (float*)d_out;
    hipLaunchKernelGGL(ham_kernel, dim3(256), dim3(1024), 0, stream,
                       x0, W1, b1, W2, out);
}